// Round 2
// baseline (692.716 us; speedup 1.0000x reference)
//
#include <hip/hip_runtime.h>
#include <math.h>

#define Bv 4
#define Nv 256
#define Cv 32
#define Mv 4
#define OUTv 64
#define MCv (Mv*Cv)      // 128
#define JT 128           // j-tile in main kernel

// ---- static device scratch (immune to harness d_ws sizing/poisoning) ----
// Every region is fully overwritten each launch before any read.
__device__ __align__(16) float g_rs  [Bv * Nv * Cv];    // 32768
__device__ __align__(16) float g_cs  [Bv * Nv * Cv];    // 32768
__device__ __align__(16) float g_dgx [Bv * Nv * Cv];    // 32768
__device__ __align__(16) float g_nb  [Bv * Nv * Mv];    // 4096
__device__ __align__(16) float g_S1  [Bv * Nv * MCv];   // 131072
__device__ __align__(16) float g_S2  [Bv * Nv * MCv];   // 131072
__device__ __align__(16) float g_t0g [Bv * OUTv];       // 256
__device__ __align__(16) float g_addv[Bv * Nv * OUTv];  // 65536

// ---------------- K1: row/col/diag contractions of x ----------------
// rs[b,n,c] = (1/N) sum_i x[b,i,n,c]   (axis-1 sum)
// cs[b,n,c] = (1/N) sum_j x[b,n,j,c]   (axis-2 sum)
// dgx[b,n,c] = x[b,n,n,c]
__global__ void k_contract1(const float* __restrict__ x) {
    int n = blockIdx.x, b = blockIdx.y;
    int t = threadIdx.x, c = t & 31, sub = t >> 5;
    const float* xb = x + (size_t)b * Nv * Nv * Cv;
    float accC = 0.f, accR = 0.f;
    for (int j = sub; j < Nv; j += 8) accC += xb[(n * Nv + j) * Cv + c];
    for (int i = sub; i < Nv; i += 8) accR += xb[(i * Nv + n) * Cv + c];
    __shared__ float red[8][64];
    red[sub][c] = accC;
    red[sub][32 + c] = accR;
    __syncthreads();
    if (t < 64) {
        float s = 0.f;
        #pragma unroll
        for (int k = 0; k < 8; k++) s += red[k][t];
        s *= (1.0f / Nv);
        if (t < 32) g_cs[(b * Nv + n) * Cv + t] = s;
        else        g_rs[(b * Nv + n) * Cv + (t - 32)] = s;
    }
    if (t < 32) g_dgx[(b * Nv + n) * Cv + t] = xb[(n * Nv + n) * Cv + t];
}

// ---------------- K2: rcs/ds + neighborhood linear + sigmoid ----------------
// nb[b,n,m] = sigmoid( [rs,cs,dg]@w1_nb + b1_nb + ([rcs,ds]@w0_nb + b0_nb) )
__global__ void k_neighb(const float* __restrict__ w1, const float* __restrict__ b1,
                         const float* __restrict__ w0, const float* __restrict__ b0) {
    int b = blockIdx.x, t = threadIdx.x;
    int c = t & 31, sub = t >> 5;
    float ar = 0.f, ad = 0.f;
    for (int n = sub; n < Nv; n += 8) {
        ar += g_rs[(b * Nv + n) * Cv + c];
        ad += g_dgx[(b * Nv + n) * Cv + c];
    }
    __shared__ float red[8][64];
    __shared__ float obj0[64];   // [rcs(32), ds(32)]
    __shared__ float t0nb[4];
    red[sub][c] = ar;
    red[sub][32 + c] = ad;
    __syncthreads();
    if (t < 64) {
        float s = 0.f;
        #pragma unroll
        for (int k = 0; k < 8; k++) s += red[k][t];
        obj0[t] = s * (1.0f / Nv);
    }
    __syncthreads();
    if (t < 4) {
        float v = b0[t];
        for (int k = 0; k < 2 * Cv; k++) v += obj0[k] * w0[k * Mv + t];
        t0nb[t] = v;
    }
    __syncthreads();
    int n = t;  // 256 threads = 256 rows
    float node[4];
    #pragma unroll
    for (int m = 0; m < 4; m++) node[m] = t0nb[m] + b1[m];
    for (int cc = 0; cc < Cv; cc++) {
        float r = g_rs[(b * Nv + n) * Cv + cc];
        float s = g_cs[(b * Nv + n) * Cv + cc];
        float d = g_dgx[(b * Nv + n) * Cv + cc];
        #pragma unroll
        for (int m = 0; m < 4; m++)
            node[m] += r * w1[cc * Mv + m] + s * w1[(Cv + cc) * Mv + m] + d * w1[(2 * Cv + cc) * Mv + m];
    }
    #pragma unroll
    for (int m = 0; m < 4; m++)
        g_nb[(b * Nv + n) * Mv + m] = 1.0f / (1.0f + expf(-node[m]));
}

// ---------------- K3: nb-weighted row/col sums ----------------
// S1[b,n,m,c] = sum_i nb[b,i,m] x[b,i,n,c];  S2[b,n,m,c] = sum_j nb[b,j,m] x[b,n,j,c]
__global__ void k_wsum(const float* __restrict__ x) {
    int n = blockIdx.x, b = blockIdx.y;
    int t = threadIdx.x, c = t & 31, sub = t >> 5;
    __shared__ __align__(16) float nbl[Nv][Mv];   // 4 KB
    ((float4*)nbl)[t] = ((const float4*)(g_nb + (size_t)b * Nv * Mv))[t];
    __syncthreads();
    const float* xb = x + (size_t)b * Nv * Nv * Cv;
    float a2[4] = {0.f, 0.f, 0.f, 0.f}, a1[4] = {0.f, 0.f, 0.f, 0.f};
    for (int j = sub; j < Nv; j += 8) {
        float xv = xb[(n * Nv + j) * Cv + c];
        #pragma unroll
        for (int m = 0; m < 4; m++) a2[m] += nbl[j][m] * xv;
    }
    for (int i = sub; i < Nv; i += 8) {
        float xv = xb[(i * Nv + n) * Cv + c];
        #pragma unroll
        for (int m = 0; m < 4; m++) a1[m] += nbl[i][m] * xv;
    }
    __shared__ float red[8][128];
    #pragma unroll
    for (int m = 0; m < 4; m++) red[sub][m * 32 + c] = a2[m];
    __syncthreads();
    if (t < 128) {
        float s = 0.f;
        #pragma unroll
        for (int k = 0; k < 8; k++) s += red[k][t];
        g_S2[(size_t)(b * Nv + n) * MCv + t] = s;
    }
    __syncthreads();
    #pragma unroll
    for (int m = 0; m < 4; m++) red[sub][m * 32 + c] = a1[m];
    __syncthreads();
    if (t < 128) {
        float s = 0.f;
        #pragma unroll
        for (int k = 0; k < 8; k++) s += red[k][t];
        g_S1[(size_t)(b * Nv + n) * MCv + t] = s;
    }
}

// ---------------- K4a: global term t0[b,o] ----------------
__global__ void k_t0(const float* __restrict__ w0d, const float* __restrict__ b0d) {
    int b = blockIdx.x, t = threadIdx.x;
    int mc = t & 127, half = t >> 7;
    int m = mc >> 5, c = mc & 31;
    float ar = 0.f, ad = 0.f;
    for (int n = half; n < Nv; n += 2) {
        float nv = g_nb[(b * Nv + n) * Mv + m];
        ar += nv * g_S1[(size_t)(b * Nv + n) * MCv + mc];
        ad += nv * nv * g_dgx[(b * Nv + n) * Cv + c];
    }
    __shared__ float redr[2][128], redd[2][128];
    __shared__ float rcs2[128], ds2[128];
    redr[half][mc] = ar;
    redd[half][mc] = ad;
    __syncthreads();
    if (t < 128) {
        rcs2[t] = (redr[0][t] + redr[1][t]) * (1.0f / ((float)Nv * Nv));
        ds2[t]  = (redd[0][t] + redd[1][t]) * (1.0f / Nv);
    }
    __syncthreads();
    if (t < OUTv) {
        float v = b0d[t];
        for (int k = 0; k < MCv; k++)
            v += rcs2[k] * w0d[k * OUTv + t] + ds2[k] * w0d[(MCv + k) * OUTv + t];
        g_t0g[b * OUTv + t] = v;
    }
}

// ---------------- K4b: per-column additive term add[b,j,o] ----------------
// add = obj1d@w1d + b1d + t0 + b2d
__global__ void k_add(const float* __restrict__ w1d, const float* __restrict__ b1d,
                      const float* __restrict__ b2d) {
    int b = blockIdx.y;
    int n = blockIdx.x * 4 + (threadIdx.x >> 6);
    int o = threadIdx.x & 63;
    float acc = b1d[o] + b2d[o] + g_t0g[b * OUTv + o];
    const float invN = 1.0f / Nv;
    #pragma unroll
    for (int m = 0; m < 4; m++) {
        float nv = g_nb[(b * Nv + n) * Mv + m];
        float f = nv * invN, d2 = nv * nv;
        for (int c = 0; c < Cv; c++) {
            int mc = m * Cv + c;
            acc += f * g_S1[(size_t)(b * Nv + n) * MCv + mc] * w1d[mc * OUTv + o]
                 + f * g_S2[(size_t)(b * Nv + n) * MCv + mc] * w1d[(MCv + mc) * OUTv + o]
                 + d2 * g_dgx[(b * Nv + n) * Cv + c] * w1d[(2 * MCv + mc) * OUTv + o];
        }
    }
    g_addv[(size_t)(b * Nv + n) * OUTv + o] = acc;
}

// ---------------- K5: main term ----------------
// out[b,i,j,o] = sum_m e[m]*( sum_c x[b,i,j,c]*Wt[m*C+c,o] + x[b,j,i,c]*Wb[m*C+c,o] ) + add[b,j,o]
// e[m] = nb[b,i,m]*nb[b,j,m]
__global__ __launch_bounds__(256) void k_main(const float* __restrict__ x,
                                              const float* __restrict__ w2d,
                                              float* __restrict__ out) {
    int jt = blockIdx.x, i = blockIdx.y, b = blockIdx.z;
    int t = threadIdx.x;
    int jg = t >> 2;          // 0..63
    int oq = t & 3, o0 = oq * 16;
    __shared__ float Xt[JT * Cv];   // swizzled: [j][c ^ (j&31)]
    __shared__ float Xb[JT * Cv];
    const float* xb = x + (size_t)b * Nv * Nv * Cv;

    // stage Xt = x[b,i, jt*JT + j, :] (contiguous) ; Xb = x[b, jt*JT + j, i, :]
    {
        const float* src = xb + ((size_t)i * Nv + jt * JT) * Cv;
        for (int k = t; k < JT * Cv / 4; k += 256) {
            float4 v = ((const float4*)src)[k];
            int j = (k * 4) >> 5, c0 = (k * 4) & 31, jm = j & 31;
            Xt[j * 32 + ((c0 + 0) ^ jm)] = v.x;
            Xt[j * 32 + ((c0 + 1) ^ jm)] = v.y;
            Xt[j * 32 + ((c0 + 2) ^ jm)] = v.z;
            Xt[j * 32 + ((c0 + 3) ^ jm)] = v.w;
        }
        for (int k = t; k < JT * Cv / 4; k += 256) {
            int j = (k * 4) >> 5, c0 = (k * 4) & 31, jm = j & 31;
            float4 v = *(const float4*)(xb + ((size_t)(jt * JT + j) * Nv + i) * Cv + c0);
            Xb[j * 32 + ((c0 + 0) ^ jm)] = v.x;
            Xb[j * 32 + ((c0 + 1) ^ jm)] = v.y;
            Xb[j * 32 + ((c0 + 2) ^ jm)] = v.z;
            Xb[j * 32 + ((c0 + 3) ^ jm)] = v.w;
        }
    }
    // e factors in registers
    float e[2][4];
    {
        float4 ni = *(const float4*)(g_nb + (size_t)(b * Nv + i) * Mv);
        #pragma unroll
        for (int jj = 0; jj < 2; jj++) {
            int j = jt * JT + jg + jj * 64;
            float4 nj = *(const float4*)(g_nb + (size_t)(b * Nv + j) * Mv);
            e[jj][0] = ni.x * nj.x; e[jj][1] = ni.y * nj.y;
            e[jj][2] = ni.z * nj.z; e[jj][3] = ni.w * nj.w;
        }
    }
    __syncthreads();

    float acc[2][16];
    #pragma unroll
    for (int jj = 0; jj < 2; jj++)
        #pragma unroll
        for (int q = 0; q < 16; q++) acc[jj][q] = 0.f;

    const float* Wt = w2d;
    const float* Wb = w2d + MCv * OUTv;
    int s0 = jg & 31;           // swizzle key ((jg+64)&31 == jg&31)
    #pragma unroll
    for (int m = 0; m < 4; m++) {
        float e0 = e[0][m], e1 = e[1][m];
        #pragma unroll 4
        for (int c = 0; c < Cv; c++) {
            int mc = m * Cv + c;
            float xt0 = Xt[jg * 32 + (c ^ s0)];
            float xt1 = Xt[(jg + 64) * 32 + (c ^ s0)];
            float xb0 = Xb[jg * 32 + (c ^ s0)];
            float xb1 = Xb[(jg + 64) * 32 + (c ^ s0)];
            float at0 = e0 * xt0, at1 = e1 * xt1;
            float ab0 = e0 * xb0, ab1 = e1 * xb1;
            const float4* wt = (const float4*)(Wt + (size_t)mc * OUTv + o0);
            const float4* wb = (const float4*)(Wb + (size_t)mc * OUTv + o0);
            #pragma unroll
            for (int q = 0; q < 4; q++) {
                float4 wtv = wt[q], wbv = wb[q];
                acc[0][q * 4 + 0] += at0 * wtv.x + ab0 * wbv.x;
                acc[0][q * 4 + 1] += at0 * wtv.y + ab0 * wbv.y;
                acc[0][q * 4 + 2] += at0 * wtv.z + ab0 * wbv.z;
                acc[0][q * 4 + 3] += at0 * wtv.w + ab0 * wbv.w;
                acc[1][q * 4 + 0] += at1 * wtv.x + ab1 * wbv.x;
                acc[1][q * 4 + 1] += at1 * wtv.y + ab1 * wbv.y;
                acc[1][q * 4 + 2] += at1 * wtv.z + ab1 * wbv.z;
                acc[1][q * 4 + 3] += at1 * wtv.w + ab1 * wbv.w;
            }
        }
    }
    // epilogue: add per-column term and store
    #pragma unroll
    for (int jj = 0; jj < 2; jj++) {
        int j = jt * JT + jg + jj * 64;
        const float4* av = (const float4*)(g_addv + (size_t)(b * Nv + j) * OUTv + o0);
        float4* op = (float4*)(out + ((size_t)(b * Nv + i) * Nv + j) * OUTv + o0);
        #pragma unroll
        for (int q = 0; q < 4; q++) {
            float4 a4 = av[q];
            float4 r;
            r.x = acc[jj][q * 4 + 0] + a4.x;
            r.y = acc[jj][q * 4 + 1] + a4.y;
            r.z = acc[jj][q * 4 + 2] + a4.z;
            r.w = acc[jj][q * 4 + 3] + a4.w;
            op[q] = r;
        }
    }
}

extern "C" void kernel_launch(void* const* d_in, const int* in_sizes, int n_in,
                              void* d_out, int out_size, void* d_ws, size_t ws_size,
                              hipStream_t stream) {
    const float* x     = (const float*)d_in[0];
    const float* w1_nb = (const float*)d_in[1];
    const float* b1_nb = (const float*)d_in[2];
    const float* w0_nb = (const float*)d_in[3];
    const float* b0_nb = (const float*)d_in[4];
    const float* w2d   = (const float*)d_in[5];
    const float* b2d   = (const float*)d_in[6];
    const float* w1d   = (const float*)d_in[7];
    const float* b1d   = (const float*)d_in[8];
    const float* w0d   = (const float*)d_in[9];
    const float* b0d   = (const float*)d_in[10];
    float* out = (float*)d_out;
    (void)d_ws; (void)ws_size;

    hipLaunchKernelGGL(k_contract1, dim3(Nv, Bv), dim3(256), 0, stream, x);
    hipLaunchKernelGGL(k_neighb, dim3(Bv), dim3(256), 0, stream,
                       w1_nb, b1_nb, w0_nb, b0_nb);
    hipLaunchKernelGGL(k_wsum, dim3(Nv, Bv), dim3(256), 0, stream, x);
    hipLaunchKernelGGL(k_t0, dim3(Bv), dim3(256), 0, stream, w0d, b0d);
    hipLaunchKernelGGL(k_add, dim3(Nv / 4, Bv), dim3(256), 0, stream,
                       w1d, b1d, b2d);
    hipLaunchKernelGGL(k_main, dim3(Nv / JT, Nv, Bv), dim3(256), 0, stream,
                       x, w2d, out);
}

// Round 3
// 222.131 us; speedup vs baseline: 3.1185x; 3.1185x over previous
//
#include <hip/hip_runtime.h>
#include <math.h>

#define Bv 4
#define Nv 256
#define Cv 32
#define Mv 4
#define OUTv 64
#define MCv (Mv*Cv)      // 128

typedef _Float16 h8 __attribute__((ext_vector_type(8)));
typedef _Float16 h4 __attribute__((ext_vector_type(4)));
typedef float f4 __attribute__((ext_vector_type(4)));

// ---- static device scratch ----
__device__ __align__(16) float g_rs  [Bv * Nv * Cv];
__device__ __align__(16) float g_cs  [Bv * Nv * Cv];
__device__ __align__(16) float g_dgx [Bv * Nv * Cv];
__device__ __align__(16) float g_nb  [Bv * Nv * Mv];
__device__ __align__(16) float g_S1  [Bv * Nv * MCv];
__device__ __align__(16) float g_S2  [Bv * Nv * MCv];
__device__ __align__(16) float g_t0g [Bv * OUTv];
__device__ __align__(16) float g_addv[Bv * Nv * OUTv];
// w2d packed to f16 in MFMA B-fragment order: frag fi=(s*4+q)*64+lane holds 8
// halves B[k=s*32+(lane>>4)*8+jj][o=q*16+(lane&15)]
__device__ __align__(16) _Float16 g_wfrag[8 * 4 * 64 * 8];   // 32 KB

// ---------------- K0: pack w2d -> f16 fragment order ----------------
__global__ void k_wpack(const float* __restrict__ w2d) {
    int t = threadIdx.x;
    for (int r = 0; r < 8; r++) {
        int fi = r * 256 + t;
        int s = fi >> 8, q = (fi >> 6) & 3, lane = fi & 63;
        int k0 = s * 32 + ((lane >> 4) << 3);
        int o = q * 16 + (lane & 15);
        #pragma unroll
        for (int jj = 0; jj < 8; jj++)
            g_wfrag[fi * 8 + jj] = (_Float16)w2d[(size_t)(k0 + jj) * OUTv + o];
    }
}

// ---------------- K1: row/col/diag contractions of x (float4) ----------------
__global__ void k_contract1(const float* __restrict__ x) {
    int n = blockIdx.x, b = blockIdx.y;
    int t = threadIdx.x, c4 = t & 7, sub = t >> 3;   // 32 subs x 8 float4-cols
    const float4* xb4 = (const float4*)(x + (size_t)b * Nv * Nv * Cv);
    float4 aC = {0.f,0.f,0.f,0.f}, aR = {0.f,0.f,0.f,0.f};
    for (int j = sub; j < Nv; j += 32) {
        float4 v = xb4[(n * Nv + j) * 8 + c4];
        aC.x += v.x; aC.y += v.y; aC.z += v.z; aC.w += v.w;
    }
    for (int i = sub; i < Nv; i += 32) {
        float4 v = xb4[(i * Nv + n) * 8 + c4];
        aR.x += v.x; aR.y += v.y; aR.z += v.z; aR.w += v.w;
    }
    __shared__ float red[2][32][36];   // padded
    red[0][sub][c4*4+0] = aC.x; red[0][sub][c4*4+1] = aC.y;
    red[0][sub][c4*4+2] = aC.z; red[0][sub][c4*4+3] = aC.w;
    red[1][sub][c4*4+0] = aR.x; red[1][sub][c4*4+1] = aR.y;
    red[1][sub][c4*4+2] = aR.z; red[1][sub][c4*4+3] = aR.w;
    __syncthreads();
    if (t < 64) {
        int which = t >> 5, c = t & 31;
        float s = 0.f;
        #pragma unroll
        for (int k = 0; k < 32; k++) s += red[which][k][c];
        s *= (1.0f / Nv);
        if (which == 0) g_cs[(b * Nv + n) * Cv + c] = s;
        else            g_rs[(b * Nv + n) * Cv + c] = s;
    }
    if (t < 8) ((float4*)g_dgx)[(b * Nv + n) * 8 + t] = xb4[(n * Nv + n) * 8 + t];
}

// ---------------- K2: neighborhood linear + sigmoid ----------------
__global__ void k_neighb(const float* __restrict__ w1, const float* __restrict__ b1,
                         const float* __restrict__ w0, const float* __restrict__ b0) {
    int b = blockIdx.x, t = threadIdx.x;
    int c = t & 31, sub = t >> 5;
    float ar = 0.f, ad = 0.f;
    for (int n = sub; n < Nv; n += 8) {
        ar += g_rs[(b * Nv + n) * Cv + c];
        ad += g_dgx[(b * Nv + n) * Cv + c];
    }
    __shared__ float red[8][64];
    __shared__ float obj0[64];
    __shared__ float t0nb[4];
    red[sub][c] = ar;
    red[sub][32 + c] = ad;
    __syncthreads();
    if (t < 64) {
        float s = 0.f;
        #pragma unroll
        for (int k = 0; k < 8; k++) s += red[k][t];
        obj0[t] = s * (1.0f / Nv);
    }
    __syncthreads();
    if (t < 4) {
        float v = b0[t];
        for (int k = 0; k < 2 * Cv; k++) v += obj0[k] * w0[k * Mv + t];
        t0nb[t] = v;
    }
    __syncthreads();
    int n = t;
    float node[4];
    #pragma unroll
    for (int m = 0; m < 4; m++) node[m] = t0nb[m] + b1[m];
    for (int cc = 0; cc < Cv; cc++) {
        float r = g_rs[(b * Nv + n) * Cv + cc];
        float s = g_cs[(b * Nv + n) * Cv + cc];
        float d = g_dgx[(b * Nv + n) * Cv + cc];
        #pragma unroll
        for (int m = 0; m < 4; m++)
            node[m] += r * w1[cc * Mv + m] + s * w1[(Cv + cc) * Mv + m] + d * w1[(2 * Cv + cc) * Mv + m];
    }
    #pragma unroll
    for (int m = 0; m < 4; m++)
        g_nb[(b * Nv + n) * Mv + m] = 1.0f / (1.0f + expf(-node[m]));
}

// ---------------- K3: nb-weighted row/col sums (float4) ----------------
__global__ void k_wsum(const float* __restrict__ x) {
    int n = blockIdx.x, b = blockIdx.y;
    int t = threadIdx.x, c4 = t & 7, sub = t >> 3;
    __shared__ __align__(16) float4 nbl[Nv];
    if (t < Nv) nbl[t] = ((const float4*)(g_nb + (size_t)b * Nv * Mv))[t];
    __syncthreads();
    const float4* xb4 = (const float4*)(x + (size_t)b * Nv * Nv * Cv);
    float4 a2[4], a1[4];
    #pragma unroll
    for (int m = 0; m < 4; m++) { a2[m] = {0.f,0.f,0.f,0.f}; a1[m] = {0.f,0.f,0.f,0.f}; }
    for (int j = sub; j < Nv; j += 32) {
        float4 v = xb4[(n * Nv + j) * 8 + c4];
        float4 nv = nbl[j];
        a2[0].x += nv.x*v.x; a2[0].y += nv.x*v.y; a2[0].z += nv.x*v.z; a2[0].w += nv.x*v.w;
        a2[1].x += nv.y*v.x; a2[1].y += nv.y*v.y; a2[1].z += nv.y*v.z; a2[1].w += nv.y*v.w;
        a2[2].x += nv.z*v.x; a2[2].y += nv.z*v.y; a2[2].z += nv.z*v.z; a2[2].w += nv.z*v.w;
        a2[3].x += nv.w*v.x; a2[3].y += nv.w*v.y; a2[3].z += nv.w*v.z; a2[3].w += nv.w*v.w;
    }
    for (int i = sub; i < Nv; i += 32) {
        float4 v = xb4[(i * Nv + n) * 8 + c4];
        float4 nv = nbl[i];
        a1[0].x += nv.x*v.x; a1[0].y += nv.x*v.y; a1[0].z += nv.x*v.z; a1[0].w += nv.x*v.w;
        a1[1].x += nv.y*v.x; a1[1].y += nv.y*v.y; a1[1].z += nv.y*v.z; a1[1].w += nv.y*v.w;
        a1[2].x += nv.z*v.x; a1[2].y += nv.z*v.y; a1[2].z += nv.z*v.z; a1[2].w += nv.z*v.w;
        a1[3].x += nv.w*v.x; a1[3].y += nv.w*v.y; a1[3].z += nv.w*v.z; a1[3].w += nv.w*v.w;
    }
    __shared__ float red[32][132];
    #pragma unroll
    for (int m = 0; m < 4; m++) {
        red[sub][m*32 + c4*4+0] = a2[m].x; red[sub][m*32 + c4*4+1] = a2[m].y;
        red[sub][m*32 + c4*4+2] = a2[m].z; red[sub][m*32 + c4*4+3] = a2[m].w;
    }
    __syncthreads();
    if (t < 128) {
        float s = 0.f;
        #pragma unroll
        for (int k = 0; k < 32; k++) s += red[k][t];
        g_S2[(size_t)(b * Nv + n) * MCv + t] = s;
    }
    __syncthreads();
    #pragma unroll
    for (int m = 0; m < 4; m++) {
        red[sub][m*32 + c4*4+0] = a1[m].x; red[sub][m*32 + c4*4+1] = a1[m].y;
        red[sub][m*32 + c4*4+2] = a1[m].z; red[sub][m*32 + c4*4+3] = a1[m].w;
    }
    __syncthreads();
    if (t < 128) {
        float s = 0.f;
        #pragma unroll
        for (int k = 0; k < 32; k++) s += red[k][t];
        g_S1[(size_t)(b * Nv + n) * MCv + t] = s;
    }
}

// ---------------- K4a: global term t0[b,o] ----------------
__global__ void k_t0(const float* __restrict__ w0d, const float* __restrict__ b0d) {
    int b = blockIdx.x, t = threadIdx.x;
    int mc = t & 127, half = t >> 7;
    int m = mc >> 5, c = mc & 31;
    float ar = 0.f, ad = 0.f;
    for (int n = half; n < Nv; n += 2) {
        float nv = g_nb[(b * Nv + n) * Mv + m];
        ar += nv * g_S1[(size_t)(b * Nv + n) * MCv + mc];
        ad += nv * nv * g_dgx[(b * Nv + n) * Cv + c];
    }
    __shared__ float redr[2][128], redd[2][128];
    __shared__ float rcs2[128], ds2[128];
    redr[half][mc] = ar;
    redd[half][mc] = ad;
    __syncthreads();
    if (t < 128) {
        rcs2[t] = (redr[0][t] + redr[1][t]) * (1.0f / ((float)Nv * Nv));
        ds2[t]  = (redd[0][t] + redd[1][t]) * (1.0f / Nv);
    }
    __syncthreads();
    if (t < OUTv) {
        float v = b0d[t];
        for (int k = 0; k < MCv; k++)
            v += rcs2[k] * w0d[k * OUTv + t] + ds2[k] * w0d[(MCv + k) * OUTv + t];
        g_t0g[b * OUTv + t] = v;
    }
}

// ---------------- K4b: per-column additive term add[b,j,o] ----------------
__global__ void k_add(const float* __restrict__ w1d, const float* __restrict__ b1d,
                      const float* __restrict__ b2d) {
    int b = blockIdx.y;
    int n = blockIdx.x * 4 + (threadIdx.x >> 6);
    int o = threadIdx.x & 63;
    float acc = b1d[o] + b2d[o] + g_t0g[b * OUTv + o];
    const float invN = 1.0f / Nv;
    #pragma unroll
    for (int m = 0; m < 4; m++) {
        float nv = g_nb[(b * Nv + n) * Mv + m];
        float f = nv * invN, d2 = nv * nv;
        for (int c = 0; c < Cv; c++) {
            int mc = m * Cv + c;
            acc += f * g_S1[(size_t)(b * Nv + n) * MCv + mc] * w1d[mc * OUTv + o]
                 + f * g_S2[(size_t)(b * Nv + n) * MCv + mc] * w1d[(MCv + mc) * OUTv + o]
                 + d2 * g_dgx[(b * Nv + n) * Cv + c] * w1d[(2 * MCv + mc) * OUTv + o];
        }
    }
    g_addv[(size_t)(b * Nv + n) * OUTv + o] = acc;
}

// ---------------- K5: main term via MFMA f16 ----------------
// out[b,i,j,o] = sum_k A[j,k]*W[k,o] + add[b,j,o],
//   A[j, s*32+c] = e[j, s&3] * X_part[j,c]  (part = s>>2: Xt / Xb)
#define XPAD 40
__global__ __launch_bounds__(256) void k_main(const float* __restrict__ x,
                                              float* __restrict__ out) {
    int jt = blockIdx.x, i = blockIdx.y, b = blockIdx.z;
    int j0 = jt * 128;
    int t = threadIdx.x;
    int lane = t & 63, w = t >> 6;
    int rowA = lane & 15, quad = lane >> 4;

    __shared__ __align__(16) _Float16 Wl[8 * 4 * 64 * 8];   // 32 KB, frag order
    __shared__ __align__(16) _Float16 Xt[128 * XPAD];        // 10 KB
    __shared__ __align__(16) _Float16 Xb[128 * XPAD];        // 10 KB

    // stage W fragments (coalesced 16B copies)
    {
        const float4* src = (const float4*)g_wfrag;
        float4* dst = (float4*)Wl;
        #pragma unroll
        for (int r = 0; r < 8; r++) dst[r * 256 + t] = src[r * 256 + t];
    }
    // stage Xt = f16(x[b,i,j0+j,:]), Xb = f16(x[b,j0+j,i,:])
    {
        const float4* x4 = (const float4*)x;
        #pragma unroll
        for (int r = 0; r < 4; r++) {
            int idx = r * 256 + t;
            int j = idx >> 3, c4 = idx & 7;
            float4 v = x4[((size_t)(b * Nv + i) * Nv + j0 + j) * 8 + c4];
            h4 hv; hv[0] = (_Float16)v.x; hv[1] = (_Float16)v.y;
            hv[2] = (_Float16)v.z; hv[3] = (_Float16)v.w;
            *(h4*)&Xt[j * XPAD + c4 * 4] = hv;
            float4 u = x4[((size_t)(b * Nv + j0 + j) * Nv + i) * 8 + c4];
            h4 hu; hu[0] = (_Float16)u.x; hu[1] = (_Float16)u.y;
            hu[2] = (_Float16)u.z; hu[3] = (_Float16)u.w;
            *(h4*)&Xb[j * XPAD + c4 * 4] = hu;
        }
    }
    // e factors for this lane's two A-rows
    int jl1 = w * 32 + rowA, jl2 = jl1 + 16;
    _Float16 e1h[4], e2h[4];
    {
        const float* ni = g_nb + (size_t)(b * Nv + i) * Mv;
        const float* n1 = g_nb + (size_t)(b * Nv + j0 + jl1) * Mv;
        const float* n2 = g_nb + (size_t)(b * Nv + j0 + jl2) * Mv;
        #pragma unroll
        for (int m = 0; m < 4; m++) {
            e1h[m] = (_Float16)(ni[m] * n1[m]);
            e2h[m] = (_Float16)(ni[m] * n2[m]);
        }
    }
    __syncthreads();

    f4 acc[2][4];
    #pragma unroll
    for (int js = 0; js < 2; js++)
        #pragma unroll
        for (int q = 0; q < 4; q++) acc[js][q] = {0.f, 0.f, 0.f, 0.f};

    const h8* Wf = (const h8*)Wl;
    #pragma unroll
    for (int part = 0; part < 2; part++) {
        const _Float16* X = part ? Xb : Xt;
        h8 xv1 = *(const h8*)&X[jl1 * XPAD + quad * 8];
        h8 xv2 = *(const h8*)&X[jl2 * XPAD + quad * 8];
        #pragma unroll
        for (int m = 0; m < 4; m++) {
            h8 a1 = xv1 * e1h[m];
            h8 a2 = xv2 * e2h[m];
            int s = part * 4 + m;
            #pragma unroll
            for (int q = 0; q < 4; q++) {
                h8 bf = Wf[(s * 4 + q) * 64 + lane];
                acc[0][q] = __builtin_amdgcn_mfma_f32_16x16x32_f16(a1, bf, acc[0][q], 0, 0, 0);
                acc[1][q] = __builtin_amdgcn_mfma_f32_16x16x32_f16(a2, bf, acc[1][q], 0, 0, 0);
            }
        }
    }
    // epilogue: D[row=quad*4+reg][col=lane&15]; j = j0 + w*32 + js*16 + row, o = q*16 + col
    #pragma unroll
    for (int js = 0; js < 2; js++) {
        int jbase = j0 + w * 32 + js * 16 + quad * 4;
        #pragma unroll
        for (int q = 0; q < 4; q++) {
            int o = q * 16 + rowA;
            #pragma unroll
            for (int r = 0; r < 4; r++) {
                int j = jbase + r;
                float v = acc[js][q][r] + g_addv[(size_t)(b * Nv + j) * OUTv + o];
                out[(((size_t)(b * Nv + i)) * Nv + j) * OUTv + o] = v;
            }
        }
    }
}

extern "C" void kernel_launch(void* const* d_in, const int* in_sizes, int n_in,
                              void* d_out, int out_size, void* d_ws, size_t ws_size,
                              hipStream_t stream) {
    const float* x     = (const float*)d_in[0];
    const float* w1_nb = (const float*)d_in[1];
    const float* b1_nb = (const float*)d_in[2];
    const float* w0_nb = (const float*)d_in[3];
    const float* b0_nb = (const float*)d_in[4];
    const float* w2d   = (const float*)d_in[5];
    const float* b2d   = (const float*)d_in[6];
    const float* w1d   = (const float*)d_in[7];
    const float* b1d   = (const float*)d_in[8];
    const float* w0d   = (const float*)d_in[9];
    const float* b0d   = (const float*)d_in[10];
    float* out = (float*)d_out;
    (void)d_ws; (void)ws_size;

    hipLaunchKernelGGL(k_wpack, dim3(1), dim3(256), 0, stream, w2d);
    hipLaunchKernelGGL(k_contract1, dim3(Nv, Bv), dim3(256), 0, stream, x);
    hipLaunchKernelGGL(k_neighb, dim3(Bv), dim3(256), 0, stream,
                       w1_nb, b1_nb, w0_nb, b0_nb);
    hipLaunchKernelGGL(k_wsum, dim3(Nv, Bv), dim3(256), 0, stream, x);
    hipLaunchKernelGGL(k_t0, dim3(Bv), dim3(256), 0, stream, w0d, b0d);
    hipLaunchKernelGGL(k_add, dim3(Nv / 4, Bv), dim3(256), 0, stream,
                       w1d, b1d, b2d);
    hipLaunchKernelGGL(k_main, dim3(2, Nv, Bv), dim3(256), 0, stream, x, out);
}

// Round 4
// 186.182 us; speedup vs baseline: 3.7206x; 1.1931x over previous
//
#include <hip/hip_runtime.h>
#include <math.h>

#define Bv 4
#define Nv 256
#define Cv 32
#define Mv 4
#define OUTv 64
#define MCv (Mv*Cv)      // 128

typedef _Float16 h8 __attribute__((ext_vector_type(8)));
typedef _Float16 h4 __attribute__((ext_vector_type(4)));
typedef float f4 __attribute__((ext_vector_type(4)));

// ---- static device scratch ----
__device__ __align__(16) float g_rs  [Bv * Nv * Cv];
__device__ __align__(16) float g_cs  [Bv * Nv * Cv];
__device__ __align__(16) float g_dgx [Bv * Nv * Cv];
__device__ __align__(16) float g_nb  [Bv * Nv * Mv];
__device__ __align__(16) float g_S1  [Bv * Nv * MCv];
__device__ __align__(16) float g_S2  [Bv * Nv * MCv];
__device__ __align__(16) float g_rcs2[Bv * MCv];        // atomic accum: sum_n nb*S1
__device__ __align__(16) float g_ds2 [Bv * MCv];        // atomic accum: sum_n nb^2*dgx
__device__ __align__(16) float g_t0g [Bv * OUTv];
__device__ __align__(16) float g_addv[Bv * Nv * OUTv];
// w2d packed to f16 in MFMA B-fragment order: frag fi=(s*4+q)*64+lane holds 8
// halves B[k=s*32+(lane>>4)*8+jj][o=q*16+(lane&15)]
__device__ __align__(16) _Float16 g_wfrag[8 * 4 * 64 * 8];   // 32 KB

// ---------------- K0: pack w2d -> f16 fragment order (8 blocks) ----------------
__global__ void k_wpack(const float* __restrict__ w2d) {
    int t = threadIdx.x;
    int r = blockIdx.x;
    int fi = r * 256 + t;
    int s = fi >> 8, q = (fi >> 6) & 3, lane = fi & 63;
    int k0 = s * 32 + ((lane >> 4) << 3);
    int o = q * 16 + (lane & 15);
    #pragma unroll
    for (int jj = 0; jj < 8; jj++)
        g_wfrag[fi * 8 + jj] = (_Float16)w2d[(size_t)(k0 + jj) * OUTv + o];
}

// ---------------- K1: row/col/diag contractions of x (float4) ----------------
__global__ void k_contract1(const float* __restrict__ x) {
    int n = blockIdx.x, b = blockIdx.y;
    int t = threadIdx.x, c4 = t & 7, sub = t >> 3;   // 32 subs x 8 float4-cols
    const float4* xb4 = (const float4*)(x + (size_t)b * Nv * Nv * Cv);
    float4 aC = {0.f,0.f,0.f,0.f}, aR = {0.f,0.f,0.f,0.f};
    for (int j = sub; j < Nv; j += 32) {
        float4 v = xb4[(n * Nv + j) * 8 + c4];
        aC.x += v.x; aC.y += v.y; aC.z += v.z; aC.w += v.w;
    }
    for (int i = sub; i < Nv; i += 32) {
        float4 v = xb4[(i * Nv + n) * 8 + c4];
        aR.x += v.x; aR.y += v.y; aR.z += v.z; aR.w += v.w;
    }
    __shared__ float red[2][32][36];   // padded
    red[0][sub][c4*4+0] = aC.x; red[0][sub][c4*4+1] = aC.y;
    red[0][sub][c4*4+2] = aC.z; red[0][sub][c4*4+3] = aC.w;
    red[1][sub][c4*4+0] = aR.x; red[1][sub][c4*4+1] = aR.y;
    red[1][sub][c4*4+2] = aR.z; red[1][sub][c4*4+3] = aR.w;
    __syncthreads();
    if (t < 64) {
        int which = t >> 5, c = t & 31;
        float s = 0.f;
        #pragma unroll
        for (int k = 0; k < 32; k++) s += red[which][k][c];
        s *= (1.0f / Nv);
        if (which == 0) g_cs[(b * Nv + n) * Cv + c] = s;
        else            g_rs[(b * Nv + n) * Cv + c] = s;
    }
    if (t < 8) ((float4*)g_dgx)[(b * Nv + n) * 8 + t] = xb4[(n * Nv + n) * 8 + t];
}

// ---------------- K2: neighborhood linear + sigmoid; zeroes t0 accumulators ----
__global__ void k_neighb(const float* __restrict__ w1, const float* __restrict__ b1,
                         const float* __restrict__ w0, const float* __restrict__ b0) {
    int b = blockIdx.x, t = threadIdx.x;
    if (t < MCv) {            // zero atomic accumulators for this b (pre-k_wsum)
        g_rcs2[b * MCv + t] = 0.f;
        g_ds2 [b * MCv + t] = 0.f;
    }
    int c = t & 31, sub = t >> 5;
    float ar = 0.f, ad = 0.f;
    for (int n = sub; n < Nv; n += 8) {
        ar += g_rs[(b * Nv + n) * Cv + c];
        ad += g_dgx[(b * Nv + n) * Cv + c];
    }
    __shared__ float red[8][64];
    __shared__ float obj0[64];
    __shared__ float t0nb[4];
    red[sub][c] = ar;
    red[sub][32 + c] = ad;
    __syncthreads();
    if (t < 64) {
        float s = 0.f;
        #pragma unroll
        for (int k = 0; k < 8; k++) s += red[k][t];
        obj0[t] = s * (1.0f / Nv);
    }
    __syncthreads();
    if (t < 4) {
        float v = b0[t];
        for (int k = 0; k < 2 * Cv; k++) v += obj0[k] * w0[k * Mv + t];
        t0nb[t] = v;
    }
    __syncthreads();
    int n = t;
    float node[4];
    #pragma unroll
    for (int m = 0; m < 4; m++) node[m] = t0nb[m] + b1[m];
    for (int cc = 0; cc < Cv; cc++) {
        float r = g_rs[(b * Nv + n) * Cv + cc];
        float s = g_cs[(b * Nv + n) * Cv + cc];
        float d = g_dgx[(b * Nv + n) * Cv + cc];
        #pragma unroll
        for (int m = 0; m < 4; m++)
            node[m] += r * w1[cc * Mv + m] + s * w1[(Cv + cc) * Mv + m] + d * w1[(2 * Cv + cc) * Mv + m];
    }
    #pragma unroll
    for (int m = 0; m < 4; m++)
        g_nb[(b * Nv + n) * Mv + m] = 1.0f / (1.0f + expf(-node[m]));
}

// ---------------- K3: nb-weighted row/col sums + t0 partial reduction --------
__global__ void k_wsum(const float* __restrict__ x) {
    int n = blockIdx.x, b = blockIdx.y;
    int t = threadIdx.x, c4 = t & 7, sub = t >> 3;
    __shared__ __align__(16) float4 nbl[Nv];
    if (t < Nv) nbl[t] = ((const float4*)(g_nb + (size_t)b * Nv * Mv))[t];
    __syncthreads();
    const float4* xb4 = (const float4*)(x + (size_t)b * Nv * Nv * Cv);
    float4 a2[4], a1[4];
    #pragma unroll
    for (int m = 0; m < 4; m++) { a2[m] = {0.f,0.f,0.f,0.f}; a1[m] = {0.f,0.f,0.f,0.f}; }
    for (int j = sub; j < Nv; j += 32) {
        float4 v = xb4[(n * Nv + j) * 8 + c4];
        float4 nv = nbl[j];
        a2[0].x += nv.x*v.x; a2[0].y += nv.x*v.y; a2[0].z += nv.x*v.z; a2[0].w += nv.x*v.w;
        a2[1].x += nv.y*v.x; a2[1].y += nv.y*v.y; a2[1].z += nv.y*v.z; a2[1].w += nv.y*v.w;
        a2[2].x += nv.z*v.x; a2[2].y += nv.z*v.y; a2[2].z += nv.z*v.z; a2[2].w += nv.z*v.w;
        a2[3].x += nv.w*v.x; a2[3].y += nv.w*v.y; a2[3].z += nv.w*v.z; a2[3].w += nv.w*v.w;
    }
    for (int i = sub; i < Nv; i += 32) {
        float4 v = xb4[(i * Nv + n) * 8 + c4];
        float4 nv = nbl[i];
        a1[0].x += nv.x*v.x; a1[0].y += nv.x*v.y; a1[0].z += nv.x*v.z; a1[0].w += nv.x*v.w;
        a1[1].x += nv.y*v.x; a1[1].y += nv.y*v.y; a1[1].z += nv.y*v.z; a1[1].w += nv.y*v.w;
        a1[2].x += nv.z*v.x; a1[2].y += nv.z*v.y; a1[2].z += nv.z*v.z; a1[2].w += nv.z*v.w;
        a1[3].x += nv.w*v.x; a1[3].y += nv.w*v.y; a1[3].z += nv.w*v.z; a1[3].w += nv.w*v.w;
    }
    __shared__ float red[32][132];
    #pragma unroll
    for (int m = 0; m < 4; m++) {
        red[sub][m*32 + c4*4+0] = a2[m].x; red[sub][m*32 + c4*4+1] = a2[m].y;
        red[sub][m*32 + c4*4+2] = a2[m].z; red[sub][m*32 + c4*4+3] = a2[m].w;
    }
    __syncthreads();
    if (t < 128) {
        float s = 0.f;
        #pragma unroll
        for (int k = 0; k < 32; k++) s += red[k][t];
        g_S2[(size_t)(b * Nv + n) * MCv + t] = s;
    }
    __syncthreads();
    #pragma unroll
    for (int m = 0; m < 4; m++) {
        red[sub][m*32 + c4*4+0] = a1[m].x; red[sub][m*32 + c4*4+1] = a1[m].y;
        red[sub][m*32 + c4*4+2] = a1[m].z; red[sub][m*32 + c4*4+3] = a1[m].w;
    }
    __syncthreads();
    if (t < 128) {
        float s = 0.f;
        #pragma unroll
        for (int k = 0; k < 32; k++) s += red[k][t];
        g_S1[(size_t)(b * Nv + n) * MCv + t] = s;
        // t0 partial reduction: rcs2 += nb[n,m]*S1row; ds2 += nb[n,m]^2*dgx[n,c]
        int m = t >> 5, c = t & 31;
        float nv = ((const float*)&nbl[n])[m];
        atomicAdd(&g_rcs2[b * MCv + t], nv * s);
        atomicAdd(&g_ds2 [b * MCv + t], nv * nv * g_dgx[(b * Nv + n) * Cv + c]);
    }
}

// ---------------- K4a: global term t0[b,o] (tiny matvec) ----------------
__global__ void k_t0(const float* __restrict__ w0d, const float* __restrict__ b0d) {
    int b = blockIdx.x, t = threadIdx.x;   // 128 threads
    __shared__ float rc[MCv], ds[MCv];
    rc[t] = g_rcs2[b * MCv + t] * (1.0f / ((float)Nv * Nv));
    ds[t] = g_ds2 [b * MCv + t] * (1.0f / Nv);
    __syncthreads();
    if (t < OUTv) {
        float v = b0d[t];
        for (int k = 0; k < MCv; k++)
            v += rc[k] * w0d[k * OUTv + t] + ds[k] * w0d[(MCv + k) * OUTv + t];
        g_t0g[b * OUTv + t] = v;
    }
}

// ---------------- K4b: per-column additive term add[b,j,o] ----------------
__global__ void k_add(const float* __restrict__ w1d, const float* __restrict__ b1d,
                      const float* __restrict__ b2d) {
    int b = blockIdx.y;
    int n = blockIdx.x * 4 + (threadIdx.x >> 6);
    int o = threadIdx.x & 63;
    float acc = b1d[o] + b2d[o] + g_t0g[b * OUTv + o];
    const float invN = 1.0f / Nv;
    #pragma unroll
    for (int m = 0; m < 4; m++) {
        float nv = g_nb[(b * Nv + n) * Mv + m];
        float f = nv * invN, d2 = nv * nv;
        for (int c = 0; c < Cv; c++) {
            int mc = m * Cv + c;
            acc += f * g_S1[(size_t)(b * Nv + n) * MCv + mc] * w1d[mc * OUTv + o]
                 + f * g_S2[(size_t)(b * Nv + n) * MCv + mc] * w1d[(MCv + mc) * OUTv + o]
                 + d2 * g_dgx[(b * Nv + n) * Cv + c] * w1d[(2 * MCv + mc) * OUTv + o];
        }
    }
    g_addv[(size_t)(b * Nv + n) * OUTv + o] = acc;
}

// ---------------- K5: main term via MFMA f16 ----------------
#define XPAD 40
__global__ __launch_bounds__(256) void k_main(const float* __restrict__ x,
                                              float* __restrict__ out) {
    int jt = blockIdx.x, i = blockIdx.y, b = blockIdx.z;
    int j0 = jt * 128;
    int t = threadIdx.x;
    int lane = t & 63, w = t >> 6;
    int rowA = lane & 15, quad = lane >> 4;

    __shared__ __align__(16) _Float16 Wl[8 * 4 * 64 * 8];   // 32 KB, frag order
    __shared__ __align__(16) _Float16 Xt[128 * XPAD];        // 10 KB
    __shared__ __align__(16) _Float16 Xb[128 * XPAD];        // 10 KB

    {
        const float4* src = (const float4*)g_wfrag;
        float4* dst = (float4*)Wl;
        #pragma unroll
        for (int r = 0; r < 8; r++) dst[r * 256 + t] = src[r * 256 + t];
    }
    {
        const float4* x4 = (const float4*)x;
        #pragma unroll
        for (int r = 0; r < 4; r++) {
            int idx = r * 256 + t;
            int j = idx >> 3, c4 = idx & 7;
            float4 v = x4[((size_t)(b * Nv + i) * Nv + j0 + j) * 8 + c4];
            h4 hv; hv[0] = (_Float16)v.x; hv[1] = (_Float16)v.y;
            hv[2] = (_Float16)v.z; hv[3] = (_Float16)v.w;
            *(h4*)&Xt[j * XPAD + c4 * 4] = hv;
            float4 u = x4[((size_t)(b * Nv + j0 + j) * Nv + i) * 8 + c4];
            h4 hu; hu[0] = (_Float16)u.x; hu[1] = (_Float16)u.y;
            hu[2] = (_Float16)u.z; hu[3] = (_Float16)u.w;
            *(h4*)&Xb[j * XPAD + c4 * 4] = hu;
        }
    }
    int jl1 = w * 32 + rowA, jl2 = jl1 + 16;
    _Float16 e1h[4], e2h[4];
    {
        const float* ni = g_nb + (size_t)(b * Nv + i) * Mv;
        const float* n1 = g_nb + (size_t)(b * Nv + j0 + jl1) * Mv;
        const float* n2 = g_nb + (size_t)(b * Nv + j0 + jl2) * Mv;
        #pragma unroll
        for (int m = 0; m < 4; m++) {
            e1h[m] = (_Float16)(ni[m] * n1[m]);
            e2h[m] = (_Float16)(ni[m] * n2[m]);
        }
    }
    __syncthreads();

    f4 acc[2][4];
    #pragma unroll
    for (int js = 0; js < 2; js++)
        #pragma unroll
        for (int q = 0; q < 4; q++) acc[js][q] = {0.f, 0.f, 0.f, 0.f};

    const h8* Wf = (const h8*)Wl;
    #pragma unroll
    for (int part = 0; part < 2; part++) {
        const _Float16* X = part ? Xb : Xt;
        h8 xv1 = *(const h8*)&X[jl1 * XPAD + quad * 8];
        h8 xv2 = *(const h8*)&X[jl2 * XPAD + quad * 8];
        #pragma unroll
        for (int m = 0; m < 4; m++) {
            h8 a1 = xv1 * e1h[m];
            h8 a2 = xv2 * e2h[m];
            int s = part * 4 + m;
            #pragma unroll
            for (int q = 0; q < 4; q++) {
                h8 bf = Wf[(s * 4 + q) * 64 + lane];
                acc[0][q] = __builtin_amdgcn_mfma_f32_16x16x32_f16(a1, bf, acc[0][q], 0, 0, 0);
                acc[1][q] = __builtin_amdgcn_mfma_f32_16x16x32_f16(a2, bf, acc[1][q], 0, 0, 0);
            }
        }
    }
    #pragma unroll
    for (int js = 0; js < 2; js++) {
        int jbase = j0 + w * 32 + js * 16 + quad * 4;
        #pragma unroll
        for (int q = 0; q < 4; q++) {
            int o = q * 16 + rowA;
            #pragma unroll
            for (int r = 0; r < 4; r++) {
                int j = jbase + r;
                float v = acc[js][q][r] + g_addv[(size_t)(b * Nv + j) * OUTv + o];
                out[(((size_t)(b * Nv + i)) * Nv + j) * OUTv + o] = v;
            }
        }
    }
}

extern "C" void kernel_launch(void* const* d_in, const int* in_sizes, int n_in,
                              void* d_out, int out_size, void* d_ws, size_t ws_size,
                              hipStream_t stream) {
    const float* x     = (const float*)d_in[0];
    const float* w1_nb = (const float*)d_in[1];
    const float* b1_nb = (const float*)d_in[2];
    const float* w0_nb = (const float*)d_in[3];
    const float* b0_nb = (const float*)d_in[4];
    const float* w2d   = (const float*)d_in[5];
    const float* b2d   = (const float*)d_in[6];
    const float* w1d   = (const float*)d_in[7];
    const float* b1d   = (const float*)d_in[8];
    const float* w0d   = (const float*)d_in[9];
    const float* b0d   = (const float*)d_in[10];
    float* out = (float*)d_out;
    (void)d_ws; (void)ws_size;

    hipLaunchKernelGGL(k_wpack, dim3(8), dim3(256), 0, stream, w2d);
    hipLaunchKernelGGL(k_contract1, dim3(Nv, Bv), dim3(256), 0, stream, x);
    hipLaunchKernelGGL(k_neighb, dim3(Bv), dim3(256), 0, stream,
                       w1_nb, b1_nb, w0_nb, b0_nb);
    hipLaunchKernelGGL(k_wsum, dim3(Nv, Bv), dim3(256), 0, stream, x);
    hipLaunchKernelGGL(k_t0, dim3(Bv), dim3(128), 0, stream, w0d, b0d);
    hipLaunchKernelGGL(k_add, dim3(Nv / 4, Bv), dim3(256), 0, stream,
                       w1d, b1d, b2d);
    hipLaunchKernelGGL(k_main, dim3(2, Nv, Bv), dim3(256), 0, stream, x, out);
}